// Round 7
// baseline (413.530 us; speedup 1.0000x reference)
//
#include <hip/hip_runtime.h>
#include <hip/hip_bf16.h>

#define N_NODES 50000
#define N_EDGES 800000
#define NBK 391          // ceil(50000/128) row buckets of 128 rows

static inline int cdiv(int a, int b) { return (a + b - 1) / b; }

typedef __attribute__((ext_vector_type(8))) short short8;
typedef __attribute__((ext_vector_type(4))) float f32x4;

__device__ __forceinline__ float b2f(unsigned short u) {
    union { unsigned int i; float f; } c;
    c.i = ((unsigned int)u) << 16;
    return c.f;
}

// ---------------- CSR build ----------------

__global__ void hist_kernel(const int* __restrict__ row, int* __restrict__ counts, int E) {
    int e = blockIdx.x * 256 + threadIdx.x;
    if (e < E) atomicAdd(&counts[row[e]], 1);
}

__global__ __launch_bounds__(256)
void scan1_kernel(const int* __restrict__ counts, int* __restrict__ row_ptr,
                  int* __restrict__ blocksums, int n) {
    __shared__ int s[256];
    int t = threadIdx.x;
    int base = blockIdx.x * 1024 + t * 4;
    int4 v = {0, 0, 0, 0};
    if (base + 3 < n) v = *(const int4*)&counts[base];
    else {
        if (base + 0 < n) v.x = counts[base + 0];
        if (base + 1 < n) v.y = counts[base + 1];
        if (base + 2 < n) v.z = counts[base + 2];
        if (base + 3 < n) v.w = counts[base + 3];
    }
    int sum = v.x + v.y + v.z + v.w;
    s[t] = sum;
    __syncthreads();
    for (int off = 1; off < 256; off <<= 1) {
        int u = (t >= off) ? s[t - off] : 0;
        __syncthreads();
        s[t] += u;
        __syncthreads();
    }
    int ex = s[t] - sum;
    int4 o;
    o.x = ex;
    o.y = ex + v.x;
    o.z = o.y + v.y;
    o.w = o.z + v.z;
    if (base + 3 < n) *(int4*)&row_ptr[base] = o;
    else {
        if (base + 0 < n) row_ptr[base + 0] = o.x;
        if (base + 1 < n) row_ptr[base + 1] = o.y;
        if (base + 2 < n) row_ptr[base + 2] = o.z;
        if (base + 3 < n) row_ptr[base + 3] = o.w;
    }
    if (t == 255) blocksums[blockIdx.x] = s[255];
}

__global__ __launch_bounds__(64)
void scan2_kernel(int* __restrict__ blocksums, int nb) {
    int t = threadIdx.x;
    int v = (t < nb) ? blocksums[t] : 0;
#pragma unroll
    for (int off = 1; off < 64; off <<= 1) {
        int u = __shfl_up(v, off);
        if (t >= off) v += u;
    }
    if (t < nb) blocksums[t] = v;
}

__global__ __launch_bounds__(256)
void scan3_kernel(int* __restrict__ row_ptr, const int* __restrict__ blocksums,
                  int n, int nb) {
    int t = threadIdx.x;
    int b = blockIdx.x;
    int off = (b == 0) ? 0 : blocksums[b - 1];
    int base = b * 1024 + t * 4;
    if (b > 0) {
        if (base + 3 < n) {
            int4 v = *(int4*)&row_ptr[base];
            v.x += off; v.y += off; v.z += off; v.w += off;
            *(int4*)&row_ptr[base] = v;
        } else {
            if (base + 0 < n) row_ptr[base + 0] += off;
            if (base + 1 < n) row_ptr[base + 1] += off;
            if (base + 2 < n) row_ptr[base + 2] += off;
            if (base + 3 < n) row_ptr[base + 3] += off;
        }
    }
    if (b == nb - 1 && t == 255) row_ptr[n] = blocksums[nb - 1];
}

__global__ void binit_kernel(const int* __restrict__ row_ptr, int* __restrict__ bcursor) {
    int b = blockIdx.x * 256 + threadIdx.x;
    if (b < NBK) bcursor[b] = row_ptr[b << 7];
}

__global__ __launch_bounds__(256)
void binA_kernel(const int* __restrict__ row, const int* __restrict__ col,
                 const float* __restrict__ vals, int* __restrict__ bcursor,
                 int2* __restrict__ tmp, int E) {
    __shared__ int hist[NBK];
    __shared__ int base[NBK];
    const int CH = 4096;
    int e0 = blockIdx.x * CH;
    for (int i = threadIdx.x; i < NBK; i += 256) hist[i] = 0;
    __syncthreads();
    for (int i = threadIdx.x; i < CH; i += 256) {
        int e = e0 + i;
        if (e < E) atomicAdd(&hist[row[e] >> 7], 1);
    }
    __syncthreads();
    for (int i = threadIdx.x; i < NBK; i += 256) {
        int c = hist[i];
        base[i] = (c > 0) ? atomicAdd(&bcursor[i], c) : 0;
        hist[i] = 0;
    }
    __syncthreads();
    for (int i = threadIdx.x; i < CH; i += 256) {
        int e = e0 + i;
        if (e < E) {
            int r = row[e];
            int b = r >> 7;
            int rk = atomicAdd(&hist[b], 1);
            tmp[base[b] + rk] = make_int2(((r & 127) << 16) | col[e],
                                          __float_as_int(vals[e]));
        }
    }
}

__global__ __launch_bounds__(256)
void binB_kernel(const int2* __restrict__ tmp, const int* __restrict__ row_ptr,
                 int2* __restrict__ epack, int N) {
    int b = blockIdx.x;
    int r0 = b << 7;
    int nr = N - r0; if (nr > 128) nr = 128;
    __shared__ int cur[128];
    int t = threadIdx.x;
    if (t < 128) cur[t] = (t < nr) ? row_ptr[r0 + t] : 0;
    __syncthreads();
    int start = row_ptr[r0];
    int end = row_ptr[r0 + nr];
    for (int i = start + t; i < end; i += 256) {
        int2 v = tmp[i];
        int rl = v.x >> 16;
        int c = v.x & 0xffff;
        int pos = atomicAdd(&cur[rl], 1);
        epack[pos] = make_int2(c, v.y);
    }
}

// ---------------- converts / packing ----------------

__global__ void f2b_kernel(const float* __restrict__ in, __hip_bfloat16* __restrict__ out, int n) {
    int i = (blockIdx.x * 256 + threadIdx.x) * 4;
    if (i >= n) return;
    float4 v = *(const float4*)&in[i];
    __hip_bfloat16 h[4] = {__float2bfloat16(v.x), __float2bfloat16(v.y),
                           __float2bfloat16(v.z), __float2bfloat16(v.w)};
    *(ushort2*)&out[i] = *(ushort2*)&h[0];
    *(ushort2*)&out[i + 2] = *(ushort2*)&h[2];
}

__device__ __forceinline__ void pack_one(const float* __restrict__ W,
                                         __hip_bfloat16* __restrict__ out,
                                         int K, int N, int t) {
    int lane = t & 63;
    int kc = (t >> 6) % (K / 32);
    int nt = (t >> 6) / (K / 32);
    int kbase = kc * 32 + (lane >> 4) * 8;
    int col = nt * 16 + (lane & 15);
    __hip_bfloat16* dst = out + (size_t)t * 8;
#pragma unroll
    for (int j = 0; j < 8; ++j)
        dst[j] = __float2bfloat16(W[(size_t)(kbase + j) * N + col]);
}

__global__ __launch_bounds__(256)
void pack_all_kernel(const float* __restrict__ W1, const float* __restrict__ W2,
                     const float* __restrict__ W3, const float* __restrict__ fcW1,
                     const float* __restrict__ fcW2,
                     __hip_bfloat16* __restrict__ pW1, __hip_bfloat16* __restrict__ pW2,
                     __hip_bfloat16* __restrict__ pW3, __hip_bfloat16* __restrict__ pfcW1,
                     __hip_bfloat16* __restrict__ pfcW2) {
    int b = blockIdx.x;
    if (b < 8)       pack_one(W1,  pW1,  128, 128, b * 256 + threadIdx.x);
    else if (b < 16) pack_one(W2,  pW2,  128, 128, (b - 8) * 256 + threadIdx.x);
    else if (b < 24) pack_one(W3,  pW3,  128, 128, (b - 16) * 256 + threadIdx.x);
    else if (b < 48) pack_one(fcW1, pfcW1, 384, 128, (b - 24) * 256 + threadIdx.x);
    else             pack_one(fcW2, pfcW2, 128, 64, (b - 48) * 256 + threadIdx.x);
}

// ---------------- bf16 MFMA GEMM (layer GEMMs) ----------------
template <int KTOT, int N, bool RELU, bool BIAS>
__global__ __launch_bounds__(256, 3)
void mfma_gemm(const __hip_bfloat16* __restrict__ A, int lda,
               const __hip_bfloat16* __restrict__ pW,
               const float* __restrict__ bias,
               __hip_bfloat16* __restrict__ C, int ldc, int M) {
    constexpr int NS = (N == 128) ? 2 : 1;
    constexpr int KC = KTOT / 32;
    __shared__ unsigned short As[64][136];
    const int tid = threadIdx.x;
    const int wave = tid >> 6;
    const int lane = tid & 63;
    const int ln15 = lane & 15;
    const int quad = lane >> 4;
    const int m0 = blockIdx.x * 64;
    const int ntw = wave * NS;

    f32x4 acc[4][NS];
#pragma unroll
    for (int s = 0; s < 4; ++s)
#pragma unroll
        for (int h = 0; h < NS; ++h) acc[s][h] = (f32x4){0.f, 0.f, 0.f, 0.f};

    for (int kb = 0; kb < KTOT / 128; ++kb) {
#pragma unroll
        for (int i = 0; i < 4; ++i) {
            int idx = tid + i * 256;
            int r = idx >> 4;
            int c8 = (idx & 15) * 8;
            uint4 v = *(const uint4*)&A[(size_t)(m0 + r) * lda + kb * 128 + c8];
            *(uint4*)&As[r][c8] = v;
        }
        __syncthreads();
#pragma unroll
        for (int kc = 0; kc < 4; ++kc) {
            short8 af[4];
#pragma unroll
            for (int s = 0; s < 4; ++s)
                af[s] = *(const short8*)&As[s * 16 + ln15][kc * 32 + quad * 8];
            short8 bf[NS];
#pragma unroll
            for (int h = 0; h < NS; ++h) {
                int kcg = kb * 4 + kc;
                bf[h] = *(const short8*)&pW[((size_t)((ntw + h) * KC + kcg) * 64 + lane) * 8];
            }
#pragma unroll
            for (int s = 0; s < 4; ++s)
#pragma unroll
                for (int h = 0; h < NS; ++h)
                    acc[s][h] = __builtin_amdgcn_mfma_f32_16x16x32_bf16(
                        af[s], bf[h], acc[s][h], 0, 0, 0);
        }
        __syncthreads();
    }

#pragma unroll
    for (int s = 0; s < 4; ++s) {
#pragma unroll
        for (int h = 0; h < NS; ++h) {
            int col = (ntw + h) * 16 + ln15;
            float bv = BIAS ? bias[col] : 0.f;
#pragma unroll
            for (int r = 0; r < 4; ++r) {
                int row = m0 + s * 16 + quad * 4 + r;
                if (row < M) {
                    float v = acc[s][h][r] + bv;
                    if (RELU) v = fmaxf(v, 0.f);
                    C[(size_t)row * ldc + col] = __float2bfloat16(v);
                }
            }
        }
    }
}

// ---------------- fused FC head ----------------
__global__ __launch_bounds__(256, 3)
void fc123_kernel(const __hip_bfloat16* __restrict__ featb,
                  const __hip_bfloat16* __restrict__ pfcW1,
                  const float* __restrict__ fcb1,
                  const __hip_bfloat16* __restrict__ pfcW2,
                  const float* __restrict__ fcb2,
                  const float* __restrict__ fcW3, const float* __restrict__ fcb3,
                  float* __restrict__ out, int M) {
    __shared__ unsigned short As[64][136];
    __shared__ float w3s[128];
    __shared__ float b3s[2];
    const int tid = threadIdx.x;
    const int wave = tid >> 6;
    const int lane = tid & 63;
    const int ln15 = lane & 15;
    const int quad = lane >> 4;
    const int m0 = blockIdx.x * 64;
    if (tid < 128) w3s[tid] = fcW3[tid];
    if (tid < 2) b3s[tid] = fcb3[tid];

    f32x4 acc[4][2];
#pragma unroll
    for (int s = 0; s < 4; ++s)
#pragma unroll
        for (int h = 0; h < 2; ++h) acc[s][h] = (f32x4){0.f, 0.f, 0.f, 0.f};
    for (int kb = 0; kb < 3; ++kb) {
#pragma unroll
        for (int i = 0; i < 4; ++i) {
            int idx = tid + i * 256;
            int r = idx >> 4;
            int c8 = (idx & 15) * 8;
            uint4 v = *(const uint4*)&featb[(size_t)(m0 + r) * 384 + kb * 128 + c8];
            *(uint4*)&As[r][c8] = v;
        }
        __syncthreads();
#pragma unroll
        for (int kc = 0; kc < 4; ++kc) {
            short8 af[4];
#pragma unroll
            for (int s = 0; s < 4; ++s)
                af[s] = *(const short8*)&As[s * 16 + ln15][kc * 32 + quad * 8];
            short8 bf[2];
#pragma unroll
            for (int h = 0; h < 2; ++h) {
                int kcg = kb * 4 + kc;
                bf[h] = *(const short8*)&pfcW1[((size_t)((wave * 2 + h) * 12 + kcg) * 64 + lane) * 8];
            }
#pragma unroll
            for (int s = 0; s < 4; ++s)
#pragma unroll
                for (int h = 0; h < 2; ++h)
                    acc[s][h] = __builtin_amdgcn_mfma_f32_16x16x32_bf16(
                        af[s], bf[h], acc[s][h], 0, 0, 0);
        }
        __syncthreads();
    }
#pragma unroll
    for (int s = 0; s < 4; ++s)
#pragma unroll
        for (int h = 0; h < 2; ++h) {
            int col = (wave * 2 + h) * 16 + ln15;
            float bv = fcb1[col];
#pragma unroll
            for (int r = 0; r < 4; ++r) {
                int row = s * 16 + quad * 4 + r;
                __hip_bfloat16 hv = __float2bfloat16(fmaxf(acc[s][h][r] + bv, 0.f));
                As[row][col] = *(unsigned short*)&hv;
            }
        }
    __syncthreads();

    f32x4 acc2[4];
#pragma unroll
    for (int s = 0; s < 4; ++s) acc2[s] = (f32x4){0.f, 0.f, 0.f, 0.f};
#pragma unroll
    for (int kc = 0; kc < 4; ++kc) {
        short8 af[4];
#pragma unroll
        for (int s = 0; s < 4; ++s)
            af[s] = *(const short8*)&As[s * 16 + ln15][kc * 32 + quad * 8];
        short8 bfw = *(const short8*)&pfcW2[((size_t)(wave * 4 + kc) * 64 + lane) * 8];
#pragma unroll
        for (int s = 0; s < 4; ++s)
            acc2[s] = __builtin_amdgcn_mfma_f32_16x16x32_bf16(af[s], bfw, acc2[s], 0, 0, 0);
    }
    __syncthreads();
    {
        int col2 = wave * 16 + ln15;
        float bv = fcb2[col2];
#pragma unroll
        for (int s = 0; s < 4; ++s)
#pragma unroll
            for (int r = 0; r < 4; ++r) {
                int row = s * 16 + quad * 4 + r;
                __hip_bfloat16 hv = __float2bfloat16(fmaxf(acc2[s][r] + bv, 0.f));
                As[row][col2] = *(unsigned short*)&hv;
            }
    }
    __syncthreads();

    if (tid < 128) {
        int row = tid >> 1, cls = tid & 1;
        int grow = m0 + row;
        if (grow < M) {
            float a = b3s[cls];
#pragma unroll
            for (int k = 0; k < 64; ++k)
                a += b2f(As[row][k]) * w3s[k * 2 + cls];
            out[(size_t)grow * 2 + cls] = a;
        }
    }
}

// ---------------- SpMM, column-blocked for per-XCD L2 residency ----------------
// Pass cb handles 32 dims [cb*32, cb*32+32): working set 50000*32*2B = 3.2MB < 4MB L2.
// 8 lanes per node (ushort4 each = 64B/edge), 32 nodes per 256-thread block.
__global__ __launch_bounds__(256)
void spmm_cb_kernel(const int* __restrict__ row_ptr, const int2* __restrict__ epack,
                    const __hip_bfloat16* __restrict__ support,
                    const float* __restrict__ bias, __hip_bfloat16* __restrict__ out,
                    int ldo, int n, int cb) {
    int t = threadIdx.x;
    int sub = t >> 3;          // 0..31 node slot
    int l8 = t & 7;            // 0..7 lane in group
    int node = blockIdx.x * 32 + sub;
    if (node >= n) return;
    int start = row_ptr[node], end = row_ptr[node + 1];
    int co = cb * 32 + l8 * 4;
    float4 acc = {0.f, 0.f, 0.f, 0.f};
    int p = start;
    for (; p + 4 <= end; p += 4) {
        int2 e0 = epack[p], e1 = epack[p + 1], e2 = epack[p + 2], e3 = epack[p + 3];
        ushort4 u0 = *(const ushort4*)&support[(size_t)e0.x * 128 + co];
        ushort4 u1 = *(const ushort4*)&support[(size_t)e1.x * 128 + co];
        ushort4 u2 = *(const ushort4*)&support[(size_t)e2.x * 128 + co];
        ushort4 u3 = *(const ushort4*)&support[(size_t)e3.x * 128 + co];
        float v0 = __int_as_float(e0.y), v1 = __int_as_float(e1.y);
        float v2 = __int_as_float(e2.y), v3 = __int_as_float(e3.y);
        acc.x += v0 * b2f(u0.x); acc.y += v0 * b2f(u0.y);
        acc.z += v0 * b2f(u0.z); acc.w += v0 * b2f(u0.w);
        acc.x += v1 * b2f(u1.x); acc.y += v1 * b2f(u1.y);
        acc.z += v1 * b2f(u1.z); acc.w += v1 * b2f(u1.w);
        acc.x += v2 * b2f(u2.x); acc.y += v2 * b2f(u2.y);
        acc.z += v2 * b2f(u2.z); acc.w += v2 * b2f(u2.w);
        acc.x += v3 * b2f(u3.x); acc.y += v3 * b2f(u3.y);
        acc.z += v3 * b2f(u3.z); acc.w += v3 * b2f(u3.w);
    }
    for (; p < end; ++p) {
        int2 e0 = epack[p];
        float v0 = __int_as_float(e0.y);
        ushort4 u0 = *(const ushort4*)&support[(size_t)e0.x * 128 + co];
        acc.x += v0 * b2f(u0.x); acc.y += v0 * b2f(u0.y);
        acc.z += v0 * b2f(u0.z); acc.w += v0 * b2f(u0.w);
    }
    float4 b = *(const float4*)&bias[co];
    __hip_bfloat16 o[4];
    o[0] = __float2bfloat16(fmaxf(acc.x + b.x, 0.f));
    o[1] = __float2bfloat16(fmaxf(acc.y + b.y, 0.f));
    o[2] = __float2bfloat16(fmaxf(acc.z + b.z, 0.f));
    o[3] = __float2bfloat16(fmaxf(acc.w + b.w, 0.f));
    *(ushort4*)&out[(size_t)node * ldo + co] = *(ushort4*)&o[0];
}

extern "C" void kernel_launch(void* const* d_in, const int* in_sizes, int n_in,
                              void* d_out, int out_size, void* d_ws, size_t ws_size,
                              hipStream_t stream) {
    const int*   adj_row  = (const int*)d_in[0];
    const int*   adj_col  = (const int*)d_in[1];
    const float* adj_vals = (const float*)d_in[2];
    const float* x        = (const float*)d_in[3];
    const float* W1   = (const float*)d_in[5];
    const float* b1   = (const float*)d_in[6];
    const float* W2   = (const float*)d_in[7];
    const float* b2   = (const float*)d_in[8];
    const float* W3   = (const float*)d_in[9];
    const float* b3   = (const float*)d_in[10];
    const float* fcW1 = (const float*)d_in[11];
    const float* fcb1 = (const float*)d_in[12];
    const float* fcW2 = (const float*)d_in[13];
    const float* fcb2 = (const float*)d_in[14];
    const float* fcW3 = (const float*)d_in[15];
    const float* fcb3 = (const float*)d_in[16];
    float* out = (float*)d_out;

    const int N = N_NODES, E = N_EDGES;
    const int Mpad = 50048;
    const int NB = cdiv(N, 1024);

    char* p = (char*)d_ws;
    auto alloc = [&](size_t bytes) {
        char* q = p;
        p += (bytes + 255) & ~(size_t)255;
        return q;
    };
    __hip_bfloat16* featb    = (__hip_bfloat16*)alloc((size_t)Mpad * 384 * 2);
    __hip_bfloat16* xb       = (__hip_bfloat16*)alloc((size_t)Mpad * 128 * 2);
    __hip_bfloat16* supportb = (__hip_bfloat16*)alloc((size_t)Mpad * 128 * 2);
    __hip_bfloat16* pW1   = (__hip_bfloat16*)alloc(16384 * 2);
    __hip_bfloat16* pW2   = (__hip_bfloat16*)alloc(16384 * 2);
    __hip_bfloat16* pW3   = (__hip_bfloat16*)alloc(16384 * 2);
    __hip_bfloat16* pfcW1 = (__hip_bfloat16*)alloc(49152 * 2);
    __hip_bfloat16* pfcW2 = (__hip_bfloat16*)alloc(8192 * 2);
    int*   row_ptr   = (int*)alloc((size_t)(N + 1) * 4);
    int*   cursor    = (int*)alloc((size_t)(N + 4) * 4);
    int*   blocksums = (int*)alloc(64 * 4);
    int*   bcursor   = (int*)alloc((size_t)NBK * 4);
    int2*  epack     = (int2*)alloc((size_t)E * 8);
    int2*  tmp = (int2*)(featb + (size_t)Mpad * 384 - (size_t)E * 4);

    // ---- CSR build (binned two-phase scatter) ----
    hipMemsetAsync(cursor, 0, (size_t)N * 4, stream);
    hist_kernel<<<cdiv(E, 256), 256, 0, stream>>>(adj_row, cursor, E);
    scan1_kernel<<<NB, 256, 0, stream>>>(cursor, row_ptr, blocksums, N);
    scan2_kernel<<<1, 64, 0, stream>>>(blocksums, NB);
    scan3_kernel<<<NB, 256, 0, stream>>>(row_ptr, blocksums, N, NB);
    binit_kernel<<<cdiv(NBK, 256), 256, 0, stream>>>(row_ptr, bcursor);
    binA_kernel<<<cdiv(E, 4096), 256, 0, stream>>>(adj_row, adj_col, adj_vals,
                                                   bcursor, tmp, E);
    binB_kernel<<<NBK, 256, 0, stream>>>(tmp, row_ptr, epack, N);

    // ---- converts & weight packing ----
    f2b_kernel<<<cdiv(N * 128 / 4, 256), 256, 0, stream>>>(x, xb, N * 128);
    pack_all_kernel<<<52, 256, 0, stream>>>(W1, W2, W3, fcW1, fcW2,
                                            pW1, pW2, pW3, pfcW1, pfcW2);

    const int gemmGrid = cdiv(N, 64);
    const int spmmGrid = cdiv(N, 32);

    // ---- GCN layer 1 ----
    mfma_gemm<128, 128, false, false><<<gemmGrid, 256, 0, stream>>>(
        xb, 128, pW1, nullptr, supportb, 128, N);
    for (int cb = 0; cb < 4; ++cb)
        spmm_cb_kernel<<<spmmGrid, 256, 0, stream>>>(row_ptr, epack, supportb, b1,
                                                     featb + 0, 384, N, cb);
    // ---- GCN layer 2 ----
    mfma_gemm<128, 128, false, false><<<gemmGrid, 256, 0, stream>>>(
        featb + 0, 384, pW2, nullptr, supportb, 128, N);
    for (int cb = 0; cb < 4; ++cb)
        spmm_cb_kernel<<<spmmGrid, 256, 0, stream>>>(row_ptr, epack, supportb, b2,
                                                     featb + 128, 384, N, cb);
    // ---- GCN layer 3 ----
    mfma_gemm<128, 128, false, false><<<gemmGrid, 256, 0, stream>>>(
        featb + 128, 384, pW3, nullptr, supportb, 128, N);
    for (int cb = 0; cb < 4; ++cb)
        spmm_cb_kernel<<<spmmGrid, 256, 0, stream>>>(row_ptr, epack, supportb, b3,
                                                     featb + 256, 384, N, cb);

    // ---- fused FC head ----
    fc123_kernel<<<gemmGrid, 256, 0, stream>>>(featb, pfcW1, fcb1, pfcW2, fcb2,
                                               fcW3, fcb3, out, N);
}

// Round 8
// 316.586 us; speedup vs baseline: 1.3062x; 1.3062x over previous
//
#include <hip/hip_runtime.h>
#include <hip/hip_bf16.h>

#define N_NODES 50000
#define N_EDGES 800000
#define NBK 391          // ceil(50000/128) row buckets of 128 rows

static inline int cdiv(int a, int b) { return (a + b - 1) / b; }

typedef __attribute__((ext_vector_type(8))) short short8;
typedef __attribute__((ext_vector_type(4))) float f32x4;

__device__ __forceinline__ float b2f(unsigned short u) {
    union { unsigned int i; float f; } c;
    c.i = ((unsigned int)u) << 16;
    return c.f;
}

// ---------------- CSR build (bucket-level only; row_ptr emitted by binB) ----------------

// bucket histogram: 391 counters, LDS-first then one global atomic per (block,bucket)
__global__ __launch_bounds__(256)
void bhist_kernel(const int* __restrict__ row, int* __restrict__ bcount, int E) {
    __shared__ int hist[NBK];
    const int CH = 4096;
    int e0 = blockIdx.x * CH;
    for (int i = threadIdx.x; i < NBK; i += 256) hist[i] = 0;
    __syncthreads();
    for (int i = threadIdx.x; i < CH; i += 256) {
        int e = e0 + i;
        if (e < E) atomicAdd(&hist[row[e] >> 7], 1);
    }
    __syncthreads();
    for (int i = threadIdx.x; i < NBK; i += 256)
        if (hist[i] > 0) atomicAdd(&bcount[i], hist[i]);
}

// one block: exclusive-scan 391 bucket counts -> bbase[0..NBK], seed bcursor
__global__ __launch_bounds__(512)
void bscan_kernel(const int* __restrict__ bcount, int* __restrict__ bbase,
                  int* __restrict__ bcursor) {
    __shared__ int s[512];
    int t = threadIdx.x;
    int v = (t < NBK) ? bcount[t] : 0;
    s[t] = v;
    __syncthreads();
    for (int off = 1; off < 512; off <<= 1) {
        int u = (t >= off) ? s[t - off] : 0;
        __syncthreads();
        s[t] += u;
        __syncthreads();
    }
    int ex = s[t] - v;
    if (t < NBK) {
        bbase[t] = ex;
        bcursor[t] = ex;
    }
    if (t == NBK - 1) bbase[NBK] = s[t];
}

// Phase A: bin edges by row>>7 into bucket-grouped tmp (bucket-contiguous).
__global__ __launch_bounds__(256)
void binA_kernel(const int* __restrict__ row, const int* __restrict__ col,
                 const float* __restrict__ vals, int* __restrict__ bcursor,
                 int2* __restrict__ tmp, int E) {
    __shared__ int hist[NBK];
    __shared__ int base[NBK];
    const int CH = 4096;
    int e0 = blockIdx.x * CH;
    for (int i = threadIdx.x; i < NBK; i += 256) hist[i] = 0;
    __syncthreads();
    for (int i = threadIdx.x; i < CH; i += 256) {
        int e = e0 + i;
        if (e < E) atomicAdd(&hist[row[e] >> 7], 1);
    }
    __syncthreads();
    for (int i = threadIdx.x; i < NBK; i += 256) {
        int c = hist[i];
        base[i] = (c > 0) ? atomicAdd(&bcursor[i], c) : 0;
        hist[i] = 0;
    }
    __syncthreads();
    for (int i = threadIdx.x; i < CH; i += 256) {
        int e = e0 + i;
        if (e < E) {
            int r = row[e];
            int b = r >> 7;
            int rk = atomicAdd(&hist[b], 1);
            tmp[base[b] + rk] = make_int2(((r & 127) << 16) | col[e],
                                          __float_as_int(vals[e]));
        }
    }
}

// Phase B: per bucket, counting-sort into exact CSR order; also emits row_ptr.
__global__ __launch_bounds__(256)
void binB_kernel(const int2* __restrict__ tmp, const int* __restrict__ bbase,
                 int* __restrict__ row_ptr, int2* __restrict__ epack, int N) {
    int b = blockIdx.x;
    int r0 = b << 7;
    int nr = N - r0; if (nr > 128) nr = 128;
    __shared__ int cnt[128];
    __shared__ int cur[128];
    int t = threadIdx.x;
    if (t < 128) cnt[t] = 0;
    __syncthreads();
    int start = bbase[b], end = bbase[b + 1];
    // pass 1: local row counts
    for (int i = start + t; i < end; i += 256)
        atomicAdd(&cnt[tmp[i].x >> 16], 1);
    __syncthreads();
    // exclusive scan of 128 counts (Hillis-Steele in cur[])
    if (t < 128) cur[t] = cnt[t];
    __syncthreads();
    for (int off = 1; off < 128; off <<= 1) {
        int u = (t >= off && t < 128) ? cur[t - off] : 0;
        __syncthreads();
        if (t < 128) cur[t] += u;
        __syncthreads();
    }
    // cur[t] is inclusive; convert to exclusive base, write row_ptr
    if (t < 128) {
        int ex = cur[t] - cnt[t];
        int pos = start + ex;
        cur[t] = pos;
        if (t < nr) row_ptr[r0 + t] = pos;
    }
    if (b == NBK - 1 && t == 128) row_ptr[N] = bbase[NBK];
    __syncthreads();
    // pass 2: place
    for (int i = start + t; i < end; i += 256) {
        int2 v = tmp[i];
        int rl = v.x >> 16;
        int c = v.x & 0xffff;
        int pos = atomicAdd(&cur[rl], 1);
        epack[pos] = make_int2(c, v.y);
    }
}

// ---------------- converts / packing (merged) ----------------

__device__ __forceinline__ void pack_one(const float* __restrict__ W,
                                         __hip_bfloat16* __restrict__ out,
                                         int K, int N, int t) {
    int lane = t & 63;
    int kc = (t >> 6) % (K / 32);
    int nt = (t >> 6) / (K / 32);
    int kbase = kc * 32 + (lane >> 4) * 8;
    int col = nt * 16 + (lane & 15);
    __hip_bfloat16* dst = out + (size_t)t * 8;
#pragma unroll
    for (int j = 0; j < 8; ++j)
        dst[j] = __float2bfloat16(W[(size_t)(kbase + j) * N + col]);
}

// blocks [0,6250): f2b of x (6.4M elems); [6250,6302): weight packing
__global__ __launch_bounds__(256)
void prep_kernel(const float* __restrict__ x, __hip_bfloat16* __restrict__ xb,
                 const float* __restrict__ W1, const float* __restrict__ W2,
                 const float* __restrict__ W3, const float* __restrict__ fcW1,
                 const float* __restrict__ fcW2,
                 __hip_bfloat16* __restrict__ pW1, __hip_bfloat16* __restrict__ pW2,
                 __hip_bfloat16* __restrict__ pW3, __hip_bfloat16* __restrict__ pfcW1,
                 __hip_bfloat16* __restrict__ pfcW2) {
    int b = blockIdx.x;
    if (b < 6250) {
        int i = (b * 256 + threadIdx.x) * 4;
        float4 v = *(const float4*)&x[i];
        __hip_bfloat16 h[4] = {__float2bfloat16(v.x), __float2bfloat16(v.y),
                               __float2bfloat16(v.z), __float2bfloat16(v.w)};
        *(ushort2*)&xb[i] = *(ushort2*)&h[0];
        *(ushort2*)&xb[i + 2] = *(ushort2*)&h[2];
        return;
    }
    b -= 6250;
    if (b < 8)       pack_one(W1,  pW1,  128, 128, b * 256 + threadIdx.x);
    else if (b < 16) pack_one(W2,  pW2,  128, 128, (b - 8) * 256 + threadIdx.x);
    else if (b < 24) pack_one(W3,  pW3,  128, 128, (b - 16) * 256 + threadIdx.x);
    else if (b < 48) pack_one(fcW1, pfcW1, 384, 128, (b - 24) * 256 + threadIdx.x);
    else             pack_one(fcW2, pfcW2, 128, 64, (b - 48) * 256 + threadIdx.x);
}

// ---------------- bf16 MFMA GEMM (layer GEMMs) ----------------
template <int KTOT, int N, bool RELU, bool BIAS>
__global__ __launch_bounds__(256, 3)
void mfma_gemm(const __hip_bfloat16* __restrict__ A, int lda,
               const __hip_bfloat16* __restrict__ pW,
               const float* __restrict__ bias,
               __hip_bfloat16* __restrict__ C, int ldc, int M) {
    constexpr int NS = (N == 128) ? 2 : 1;
    constexpr int KC = KTOT / 32;
    __shared__ unsigned short As[64][136];
    const int tid = threadIdx.x;
    const int wave = tid >> 6;
    const int lane = tid & 63;
    const int ln15 = lane & 15;
    const int quad = lane >> 4;
    const int m0 = blockIdx.x * 64;
    const int ntw = wave * NS;

    f32x4 acc[4][NS];
#pragma unroll
    for (int s = 0; s < 4; ++s)
#pragma unroll
        for (int h = 0; h < NS; ++h) acc[s][h] = (f32x4){0.f, 0.f, 0.f, 0.f};

    for (int kb = 0; kb < KTOT / 128; ++kb) {
#pragma unroll
        for (int i = 0; i < 4; ++i) {
            int idx = tid + i * 256;
            int r = idx >> 4;
            int c8 = (idx & 15) * 8;
            uint4 v = *(const uint4*)&A[(size_t)(m0 + r) * lda + kb * 128 + c8];
            *(uint4*)&As[r][c8] = v;
        }
        __syncthreads();
#pragma unroll
        for (int kc = 0; kc < 4; ++kc) {
            short8 af[4];
#pragma unroll
            for (int s = 0; s < 4; ++s)
                af[s] = *(const short8*)&As[s * 16 + ln15][kc * 32 + quad * 8];
            short8 bf[NS];
#pragma unroll
            for (int h = 0; h < NS; ++h) {
                int kcg = kb * 4 + kc;
                bf[h] = *(const short8*)&pW[((size_t)((ntw + h) * KC + kcg) * 64 + lane) * 8];
            }
#pragma unroll
            for (int s = 0; s < 4; ++s)
#pragma unroll
                for (int h = 0; h < NS; ++h)
                    acc[s][h] = __builtin_amdgcn_mfma_f32_16x16x32_bf16(
                        af[s], bf[h], acc[s][h], 0, 0, 0);
        }
        __syncthreads();
    }

#pragma unroll
    for (int s = 0; s < 4; ++s) {
#pragma unroll
        for (int h = 0; h < NS; ++h) {
            int col = (ntw + h) * 16 + ln15;
            float bv = BIAS ? bias[col] : 0.f;
#pragma unroll
            for (int r = 0; r < 4; ++r) {
                int row = m0 + s * 16 + quad * 4 + r;
                if (row < M) {
                    float v = acc[s][h][r] + bv;
                    if (RELU) v = fmaxf(v, 0.f);
                    C[(size_t)row * ldc + col] = __float2bfloat16(v);
                }
            }
        }
    }
}

// ---------------- fused FC head ----------------
__global__ __launch_bounds__(256, 3)
void fc123_kernel(const __hip_bfloat16* __restrict__ featb,
                  const __hip_bfloat16* __restrict__ pfcW1,
                  const float* __restrict__ fcb1,
                  const __hip_bfloat16* __restrict__ pfcW2,
                  const float* __restrict__ fcb2,
                  const float* __restrict__ fcW3, const float* __restrict__ fcb3,
                  float* __restrict__ out, int M) {
    __shared__ unsigned short As[64][136];
    __shared__ float w3s[128];
    __shared__ float b3s[2];
    const int tid = threadIdx.x;
    const int wave = tid >> 6;
    const int lane = tid & 63;
    const int ln15 = lane & 15;
    const int quad = lane >> 4;
    const int m0 = blockIdx.x * 64;
    if (tid < 128) w3s[tid] = fcW3[tid];
    if (tid < 2) b3s[tid] = fcb3[tid];

    f32x4 acc[4][2];
#pragma unroll
    for (int s = 0; s < 4; ++s)
#pragma unroll
        for (int h = 0; h < 2; ++h) acc[s][h] = (f32x4){0.f, 0.f, 0.f, 0.f};
    for (int kb = 0; kb < 3; ++kb) {
#pragma unroll
        for (int i = 0; i < 4; ++i) {
            int idx = tid + i * 256;
            int r = idx >> 4;
            int c8 = (idx & 15) * 8;
            uint4 v = *(const uint4*)&featb[(size_t)(m0 + r) * 384 + kb * 128 + c8];
            *(uint4*)&As[r][c8] = v;
        }
        __syncthreads();
#pragma unroll
        for (int kc = 0; kc < 4; ++kc) {
            short8 af[4];
#pragma unroll
            for (int s = 0; s < 4; ++s)
                af[s] = *(const short8*)&As[s * 16 + ln15][kc * 32 + quad * 8];
            short8 bf[2];
#pragma unroll
            for (int h = 0; h < 2; ++h) {
                int kcg = kb * 4 + kc;
                bf[h] = *(const short8*)&pfcW1[((size_t)((wave * 2 + h) * 12 + kcg) * 64 + lane) * 8];
            }
#pragma unroll
            for (int s = 0; s < 4; ++s)
#pragma unroll
                for (int h = 0; h < 2; ++h)
                    acc[s][h] = __builtin_amdgcn_mfma_f32_16x16x32_bf16(
                        af[s], bf[h], acc[s][h], 0, 0, 0);
        }
        __syncthreads();
    }
#pragma unroll
    for (int s = 0; s < 4; ++s)
#pragma unroll
        for (int h = 0; h < 2; ++h) {
            int col = (wave * 2 + h) * 16 + ln15;
            float bv = fcb1[col];
#pragma unroll
            for (int r = 0; r < 4; ++r) {
                int row = s * 16 + quad * 4 + r;
                __hip_bfloat16 hv = __float2bfloat16(fmaxf(acc[s][h][r] + bv, 0.f));
                As[row][col] = *(unsigned short*)&hv;
            }
        }
    __syncthreads();

    f32x4 acc2[4];
#pragma unroll
    for (int s = 0; s < 4; ++s) acc2[s] = (f32x4){0.f, 0.f, 0.f, 0.f};
#pragma unroll
    for (int kc = 0; kc < 4; ++kc) {
        short8 af[4];
#pragma unroll
        for (int s = 0; s < 4; ++s)
            af[s] = *(const short8*)&As[s * 16 + ln15][kc * 32 + quad * 8];
        short8 bfw = *(const short8*)&pfcW2[((size_t)(wave * 4 + kc) * 64 + lane) * 8];
#pragma unroll
        for (int s = 0; s < 4; ++s)
            acc2[s] = __builtin_amdgcn_mfma_f32_16x16x32_bf16(af[s], bfw, acc2[s], 0, 0, 0);
    }
    __syncthreads();
    {
        int col2 = wave * 16 + ln15;
        float bv = fcb2[col2];
#pragma unroll
        for (int s = 0; s < 4; ++s)
#pragma unroll
            for (int r = 0; r < 4; ++r) {
                int row = s * 16 + quad * 4 + r;
                __hip_bfloat16 hv = __float2bfloat16(fmaxf(acc2[s][r] + bv, 0.f));
                As[row][col2] = *(unsigned short*)&hv;
            }
    }
    __syncthreads();

    if (tid < 128) {
        int row = tid >> 1, cls = tid & 1;
        int grow = m0 + row;
        if (grow < M) {
            float a = b3s[cls];
#pragma unroll
            for (int k = 0; k < 64; ++k)
                a += b2f(As[row][k]) * w3s[k * 2 + cls];
            out[(size_t)grow * 2 + cls] = a;
        }
    }
}

// ---------------- SpMM (round-6 form: 32 lanes/node, single pass) ----------------
__global__ __launch_bounds__(256)
void spmm_kernel(const int* __restrict__ row_ptr, const int2* __restrict__ epack,
                 const __hip_bfloat16* __restrict__ support,
                 const float* __restrict__ bias, __hip_bfloat16* __restrict__ out,
                 int ldo, int n) {
    int t = threadIdx.x;
    int sub = t >> 5;
    int l = t & 31;
    int node = blockIdx.x * 8 + sub;
    if (node >= n) return;
    int start = row_ptr[node], end = row_ptr[node + 1];
    float4 acc = {0.f, 0.f, 0.f, 0.f};
    int p = start;
    for (; p + 2 <= end; p += 2) {
        int2 e0 = epack[p], e1 = epack[p + 1];
        float v0 = __int_as_float(e0.y), v1 = __int_as_float(e1.y);
        ushort4 u0 = *(const ushort4*)&support[(size_t)e0.x * 128 + l * 4];
        ushort4 u1 = *(const ushort4*)&support[(size_t)e1.x * 128 + l * 4];
        acc.x += v0 * b2f(u0.x); acc.y += v0 * b2f(u0.y);
        acc.z += v0 * b2f(u0.z); acc.w += v0 * b2f(u0.w);
        acc.x += v1 * b2f(u1.x); acc.y += v1 * b2f(u1.y);
        acc.z += v1 * b2f(u1.z); acc.w += v1 * b2f(u1.w);
    }
    if (p < end) {
        int2 e0 = epack[p];
        float v0 = __int_as_float(e0.y);
        ushort4 u0 = *(const ushort4*)&support[(size_t)e0.x * 128 + l * 4];
        acc.x += v0 * b2f(u0.x); acc.y += v0 * b2f(u0.y);
        acc.z += v0 * b2f(u0.z); acc.w += v0 * b2f(u0.w);
    }
    float4 b = *(const float4*)&bias[l * 4];
    __hip_bfloat16 o[4];
    o[0] = __float2bfloat16(fmaxf(acc.x + b.x, 0.f));
    o[1] = __float2bfloat16(fmaxf(acc.y + b.y, 0.f));
    o[2] = __float2bfloat16(fmaxf(acc.z + b.z, 0.f));
    o[3] = __float2bfloat16(fmaxf(acc.w + b.w, 0.f));
    *(ushort4*)&out[(size_t)node * ldo + l * 4] = *(ushort4*)&o[0];
}

extern "C" void kernel_launch(void* const* d_in, const int* in_sizes, int n_in,
                              void* d_out, int out_size, void* d_ws, size_t ws_size,
                              hipStream_t stream) {
    const int*   adj_row  = (const int*)d_in[0];
    const int*   adj_col  = (const int*)d_in[1];
    const float* adj_vals = (const float*)d_in[2];
    const float* x        = (const float*)d_in[3];
    const float* W1   = (const float*)d_in[5];
    const float* b1   = (const float*)d_in[6];
    const float* W2   = (const float*)d_in[7];
    const float* b2   = (const float*)d_in[8];
    const float* W3   = (const float*)d_in[9];
    const float* b3   = (const float*)d_in[10];
    const float* fcW1 = (const float*)d_in[11];
    const float* fcb1 = (const float*)d_in[12];
    const float* fcW2 = (const float*)d_in[13];
    const float* fcb2 = (const float*)d_in[14];
    const float* fcW3 = (const float*)d_in[15];
    const float* fcb3 = (const float*)d_in[16];
    float* out = (float*)d_out;

    const int N = N_NODES, E = N_EDGES;
    const int Mpad = 50048;

    char* p = (char*)d_ws;
    auto alloc = [&](size_t bytes) {
        char* q = p;
        p += (bytes + 255) & ~(size_t)255;
        return q;
    };
    __hip_bfloat16* featb    = (__hip_bfloat16*)alloc((size_t)Mpad * 384 * 2);
    __hip_bfloat16* xb       = (__hip_bfloat16*)alloc((size_t)Mpad * 128 * 2);
    __hip_bfloat16* supportb = (__hip_bfloat16*)alloc((size_t)Mpad * 128 * 2);
    __hip_bfloat16* pW1   = (__hip_bfloat16*)alloc(16384 * 2);
    __hip_bfloat16* pW2   = (__hip_bfloat16*)alloc(16384 * 2);
    __hip_bfloat16* pW3   = (__hip_bfloat16*)alloc(16384 * 2);
    __hip_bfloat16* pfcW1 = (__hip_bfloat16*)alloc(49152 * 2);
    __hip_bfloat16* pfcW2 = (__hip_bfloat16*)alloc(8192 * 2);
    int*   row_ptr   = (int*)alloc((size_t)(N + 1) * 4);
    int*   bcount    = (int*)alloc((size_t)NBK * 4);
    int*   bbase     = (int*)alloc((size_t)(NBK + 1) * 4);
    int*   bcursor   = (int*)alloc((size_t)NBK * 4);
    int2*  epack     = (int2*)alloc((size_t)E * 8);
    int2*  tmp = (int2*)(featb + (size_t)Mpad * 384 - (size_t)E * 4);

    // ---- CSR build: bucket hist -> scan -> bin -> counting-sort (emits row_ptr) ----
    hipMemsetAsync(bcount, 0, (size_t)NBK * 4, stream);
    bhist_kernel<<<cdiv(E, 4096), 256, 0, stream>>>(adj_row, bcount, E);
    bscan_kernel<<<1, 512, 0, stream>>>(bcount, bbase, bcursor);
    binA_kernel<<<cdiv(E, 4096), 256, 0, stream>>>(adj_row, adj_col, adj_vals,
                                                   bcursor, tmp, E);
    binB_kernel<<<NBK, 256, 0, stream>>>(tmp, bbase, row_ptr, epack, N);

    // ---- converts & weight packing (one launch) ----
    prep_kernel<<<6302, 256, 0, stream>>>(x, xb, W1, W2, W3, fcW1, fcW2,
                                          pW1, pW2, pW3, pfcW1, pfcW2);

    const int gemmGrid = cdiv(N, 64);
    const int spmmGrid = cdiv(N, 8);

    // ---- GCN layer 1 ----
    mfma_gemm<128, 128, false, false><<<gemmGrid, 256, 0, stream>>>(
        xb, 128, pW1, nullptr, supportb, 128, N);
    spmm_kernel<<<spmmGrid, 256, 0, stream>>>(row_ptr, epack, supportb, b1,
                                              featb + 0, 384, N);
    // ---- GCN layer 2 ----
    mfma_gemm<128, 128, false, false><<<gemmGrid, 256, 0, stream>>>(
        featb + 0, 384, pW2, nullptr, supportb, 128, N);
    spmm_kernel<<<spmmGrid, 256, 0, stream>>>(row_ptr, epack, supportb, b2,
                                              featb + 128, 384, N);
    // ---- GCN layer 3 ----
    mfma_gemm<128, 128, false, false><<<gemmGrid, 256, 0, stream>>>(
        featb + 128, 384, pW3, nullptr, supportb, 128, N);
    spmm_kernel<<<spmmGrid, 256, 0, stream>>>(row_ptr, epack, supportb, b3,
                                              featb + 256, 384, N);

    // ---- fused FC head ----
    fc123_kernel<<<gemmGrid, 256, 0, stream>>>(featb, pfcW1, fcb1, pfcW2, fcb2,
                                               fcW3, fcb3, out, N);
}

// Round 9
// 302.587 us; speedup vs baseline: 1.3666x; 1.0463x over previous
//
#include <hip/hip_runtime.h>
#include <hip/hip_bf16.h>

#define N_NODES 50000
#define N_EDGES 800000
#define NBK 391          // ceil(50000/128) row buckets of 128 rows
#define BCAP 2560        // slab capacity per bucket (mean 2048 + 11 sigma)

static inline int cdiv(int a, int b) { return (a + b - 1) / b; }

typedef __attribute__((ext_vector_type(8))) short short8;
typedef __attribute__((ext_vector_type(4))) float f32x4;

__device__ __forceinline__ float b2f(unsigned short u) {
    union { unsigned int i; float f; } c;
    c.i = ((unsigned int)u) << 16;
    return c.f;
}
__device__ __forceinline__ unsigned short f2bb(float f) {
    __hip_bfloat16 h = __float2bfloat16(f);
    return *(unsigned short*)&h;
}

// ---------------- CSR build ----------------

// Phase A: bin edges by row>>7 into fixed-capacity slabs tmp[b*BCAP ...].
// bcursor pre-seeded to b*BCAP by prep_kernel.
__global__ __launch_bounds__(256)
void binA_kernel(const int* __restrict__ row, const int* __restrict__ col,
                 const float* __restrict__ vals, int* __restrict__ bcursor,
                 int2* __restrict__ tmp, int E) {
    __shared__ int hist[NBK];
    __shared__ int base[NBK];
    const int CH = 4096;
    int e0 = blockIdx.x * CH;
    for (int i = threadIdx.x; i < NBK; i += 256) hist[i] = 0;
    __syncthreads();
    for (int i = threadIdx.x; i < CH; i += 256) {
        int e = e0 + i;
        if (e < E) atomicAdd(&hist[row[e] >> 7], 1);
    }
    __syncthreads();
    for (int i = threadIdx.x; i < NBK; i += 256) {
        int c = hist[i];
        base[i] = (c > 0) ? atomicAdd(&bcursor[i], c) : 0;
        hist[i] = 0;
    }
    __syncthreads();
    for (int i = threadIdx.x; i < CH; i += 256) {
        int e = e0 + i;
        if (e < E) {
            int r = row[e];
            int b = r >> 7;
            int rk = atomicAdd(&hist[b], 1);
            tmp[base[b] + rk] = make_int2(((r & 127) << 16) | col[e],
                                          __float_as_int(vals[e]));
        }
    }
}

// exclusive-scan of slab counts (bcursor[b]-b*BCAP) -> bbase[0..NBK]
__global__ __launch_bounds__(512)
void bscan_kernel(const int* __restrict__ bcursor, int* __restrict__ bbase) {
    __shared__ int s[512];
    int t = threadIdx.x;
    int v = (t < NBK) ? (bcursor[t] - t * BCAP) : 0;
    s[t] = v;
    __syncthreads();
    for (int off = 1; off < 512; off <<= 1) {
        int u = (t >= off) ? s[t - off] : 0;
        __syncthreads();
        s[t] += u;
        __syncthreads();
    }
    if (t < NBK) bbase[t] = s[t] - v;
    if (t == NBK - 1) bbase[NBK] = s[t];
}

// Phase B: per bucket, counting-sort slab into exact CSR order; emits row_ptr.
__global__ __launch_bounds__(256)
void binB_kernel(const int2* __restrict__ tmp, const int* __restrict__ bcursor,
                 const int* __restrict__ bbase, int* __restrict__ row_ptr,
                 int2* __restrict__ epack, int N) {
    int b = blockIdx.x;
    int r0 = b << 7;
    int nr = N - r0; if (nr > 128) nr = 128;
    __shared__ int cnt[128];
    __shared__ int cur[128];
    int t = threadIdx.x;
    if (t < 128) cnt[t] = 0;
    __syncthreads();
    int slab = b * BCAP;
    int send = bcursor[b];          // slab + count
    int obase = bbase[b];
    for (int i = slab + t; i < send; i += 256)
        atomicAdd(&cnt[tmp[i].x >> 16], 1);
    __syncthreads();
    if (t < 128) cur[t] = cnt[t];
    __syncthreads();
    for (int off = 1; off < 128; off <<= 1) {
        int u = (t >= off && t < 128) ? cur[t - off] : 0;
        __syncthreads();
        if (t < 128) cur[t] += u;
        __syncthreads();
    }
    if (t < 128) {
        int ex = cur[t] - cnt[t];
        int pos = obase + ex;
        cur[t] = pos;
        if (t < nr) row_ptr[r0 + t] = pos;
    }
    if (b == NBK - 1 && t == 128) row_ptr[N] = bbase[NBK];
    __syncthreads();
    for (int i = slab + t; i < send; i += 256) {
        int2 v = tmp[i];
        int rl = v.x >> 16;
        int c = v.x & 0xffff;
        int pos = atomicAdd(&cur[rl], 1);
        epack[pos] = make_int2(c, v.y);
    }
}

// ---------------- prep: weight packing + bucket-cursor init ----------------

__device__ __forceinline__ void pack_one(const float* __restrict__ W,
                                         __hip_bfloat16* __restrict__ out,
                                         int K, int N, int t) {
    int lane = t & 63;
    int kc = (t >> 6) % (K / 32);
    int nt = (t >> 6) / (K / 32);
    int kbase = kc * 32 + (lane >> 4) * 8;
    int col = nt * 16 + (lane & 15);
    __hip_bfloat16* dst = out + (size_t)t * 8;
#pragma unroll
    for (int j = 0; j < 8; ++j)
        dst[j] = __float2bfloat16(W[(size_t)(kbase + j) * N + col]);
}

// blocks [0,8) W1, [8,16) W2, [16,24) W3, [24,48) fcW1, [48,52) fcW2,
// [52,54): bcursor init (391 entries)
__global__ __launch_bounds__(256)
void prep_kernel(const float* __restrict__ W1, const float* __restrict__ W2,
                 const float* __restrict__ W3, const float* __restrict__ fcW1,
                 const float* __restrict__ fcW2,
                 __hip_bfloat16* __restrict__ pW1, __hip_bfloat16* __restrict__ pW2,
                 __hip_bfloat16* __restrict__ pW3, __hip_bfloat16* __restrict__ pfcW1,
                 __hip_bfloat16* __restrict__ pfcW2, int* __restrict__ bcursor) {
    int b = blockIdx.x;
    if (b < 8)       pack_one(W1,  pW1,  128, 128, b * 256 + threadIdx.x);
    else if (b < 16) pack_one(W2,  pW2,  128, 128, (b - 8) * 256 + threadIdx.x);
    else if (b < 24) pack_one(W3,  pW3,  128, 128, (b - 16) * 256 + threadIdx.x);
    else if (b < 48) pack_one(fcW1, pfcW1, 384, 128, (b - 24) * 256 + threadIdx.x);
    else if (b < 52) pack_one(fcW2, pfcW2, 128, 64, (b - 48) * 256 + threadIdx.x);
    else {
        int t = (b - 52) * 256 + threadIdx.x;
        if (t < NBK) bcursor[t] = t * BCAP;
    }
}

// ---------------- bf16 MFMA GEMM; AFP32: stage fp32 A with convert ----------------
template <int KTOT, int N, bool RELU, bool BIAS, bool AFP32>
__global__ __launch_bounds__(256, 3)
void mfma_gemm(const void* __restrict__ Aptr, int lda,
               const __hip_bfloat16* __restrict__ pW,
               const float* __restrict__ bias,
               __hip_bfloat16* __restrict__ C, int ldc, int M) {
    constexpr int NS = (N == 128) ? 2 : 1;
    constexpr int KC = KTOT / 32;
    __shared__ unsigned short As[64][136];
    const int tid = threadIdx.x;
    const int wave = tid >> 6;
    const int lane = tid & 63;
    const int ln15 = lane & 15;
    const int quad = lane >> 4;
    const int m0 = blockIdx.x * 64;
    const int ntw = wave * NS;

    f32x4 acc[4][NS];
#pragma unroll
    for (int s = 0; s < 4; ++s)
#pragma unroll
        for (int h = 0; h < NS; ++h) acc[s][h] = (f32x4){0.f, 0.f, 0.f, 0.f};

    for (int kb = 0; kb < KTOT / 128; ++kb) {
#pragma unroll
        for (int i = 0; i < 4; ++i) {
            int idx = tid + i * 256;
            int r = idx >> 4;
            int c8 = (idx & 15) * 8;
            if constexpr (AFP32) {
                const float* A = (const float*)Aptr;
                uint4 pk = {0, 0, 0, 0};
                if (m0 + r < M) {
                    const float* src = &A[(size_t)(m0 + r) * lda + kb * 128 + c8];
                    float4 a = *(const float4*)src;
                    float4 bq = *(const float4*)(src + 4);
                    pk.x = f2bb(a.x) | ((unsigned int)f2bb(a.y) << 16);
                    pk.y = f2bb(a.z) | ((unsigned int)f2bb(a.w) << 16);
                    pk.z = f2bb(bq.x) | ((unsigned int)f2bb(bq.y) << 16);
                    pk.w = f2bb(bq.z) | ((unsigned int)f2bb(bq.w) << 16);
                }
                *(uint4*)&As[r][c8] = pk;
            } else {
                const __hip_bfloat16* A = (const __hip_bfloat16*)Aptr;
                uint4 v = *(const uint4*)&A[(size_t)(m0 + r) * lda + kb * 128 + c8];
                *(uint4*)&As[r][c8] = v;
            }
        }
        __syncthreads();
#pragma unroll
        for (int kc = 0; kc < 4; ++kc) {
            short8 af[4];
#pragma unroll
            for (int s = 0; s < 4; ++s)
                af[s] = *(const short8*)&As[s * 16 + ln15][kc * 32 + quad * 8];
            short8 bf[NS];
#pragma unroll
            for (int h = 0; h < NS; ++h) {
                int kcg = kb * 4 + kc;
                bf[h] = *(const short8*)&pW[((size_t)((ntw + h) * KC + kcg) * 64 + lane) * 8];
            }
#pragma unroll
            for (int s = 0; s < 4; ++s)
#pragma unroll
                for (int h = 0; h < NS; ++h)
                    acc[s][h] = __builtin_amdgcn_mfma_f32_16x16x32_bf16(
                        af[s], bf[h], acc[s][h], 0, 0, 0);
        }
        __syncthreads();
    }

#pragma unroll
    for (int s = 0; s < 4; ++s) {
#pragma unroll
        for (int h = 0; h < NS; ++h) {
            int col = (ntw + h) * 16 + ln15;
            float bv = BIAS ? bias[col] : 0.f;
#pragma unroll
            for (int r = 0; r < 4; ++r) {
                int row = m0 + s * 16 + quad * 4 + r;
                if (row < M) {
                    float v = acc[s][h][r] + bv;
                    if (RELU) v = fmaxf(v, 0.f);
                    C[(size_t)row * ldc + col] = __float2bfloat16(v);
                }
            }
        }
    }
}

// ---------------- fused FC head ----------------
__global__ __launch_bounds__(256, 3)
void fc123_kernel(const __hip_bfloat16* __restrict__ featb,
                  const __hip_bfloat16* __restrict__ pfcW1,
                  const float* __restrict__ fcb1,
                  const __hip_bfloat16* __restrict__ pfcW2,
                  const float* __restrict__ fcb2,
                  const float* __restrict__ fcW3, const float* __restrict__ fcb3,
                  float* __restrict__ out, int M) {
    __shared__ unsigned short As[64][136];
    __shared__ float w3s[128];
    __shared__ float b3s[2];
    const int tid = threadIdx.x;
    const int wave = tid >> 6;
    const int lane = tid & 63;
    const int ln15 = lane & 15;
    const int quad = lane >> 4;
    const int m0 = blockIdx.x * 64;
    if (tid < 128) w3s[tid] = fcW3[tid];
    if (tid < 2) b3s[tid] = fcb3[tid];

    f32x4 acc[4][2];
#pragma unroll
    for (int s = 0; s < 4; ++s)
#pragma unroll
        for (int h = 0; h < 2; ++h) acc[s][h] = (f32x4){0.f, 0.f, 0.f, 0.f};
    for (int kb = 0; kb < 3; ++kb) {
#pragma unroll
        for (int i = 0; i < 4; ++i) {
            int idx = tid + i * 256;
            int r = idx >> 4;
            int c8 = (idx & 15) * 8;
            uint4 v = *(const uint4*)&featb[(size_t)(m0 + r) * 384 + kb * 128 + c8];
            *(uint4*)&As[r][c8] = v;
        }
        __syncthreads();
#pragma unroll
        for (int kc = 0; kc < 4; ++kc) {
            short8 af[4];
#pragma unroll
            for (int s = 0; s < 4; ++s)
                af[s] = *(const short8*)&As[s * 16 + ln15][kc * 32 + quad * 8];
            short8 bf[2];
#pragma unroll
            for (int h = 0; h < 2; ++h) {
                int kcg = kb * 4 + kc;
                bf[h] = *(const short8*)&pfcW1[((size_t)((wave * 2 + h) * 12 + kcg) * 64 + lane) * 8];
            }
#pragma unroll
            for (int s = 0; s < 4; ++s)
#pragma unroll
                for (int h = 0; h < 2; ++h)
                    acc[s][h] = __builtin_amdgcn_mfma_f32_16x16x32_bf16(
                        af[s], bf[h], acc[s][h], 0, 0, 0);
        }
        __syncthreads();
    }
#pragma unroll
    for (int s = 0; s < 4; ++s)
#pragma unroll
        for (int h = 0; h < 2; ++h) {
            int col = (wave * 2 + h) * 16 + ln15;
            float bv = fcb1[col];
#pragma unroll
            for (int r = 0; r < 4; ++r) {
                int row = s * 16 + quad * 4 + r;
                As[row][col] = f2bb(fmaxf(acc[s][h][r] + bv, 0.f));
            }
        }
    __syncthreads();

    f32x4 acc2[4];
#pragma unroll
    for (int s = 0; s < 4; ++s) acc2[s] = (f32x4){0.f, 0.f, 0.f, 0.f};
#pragma unroll
    for (int kc = 0; kc < 4; ++kc) {
        short8 af[4];
#pragma unroll
        for (int s = 0; s < 4; ++s)
            af[s] = *(const short8*)&As[s * 16 + ln15][kc * 32 + quad * 8];
        short8 bfw = *(const short8*)&pfcW2[((size_t)(wave * 4 + kc) * 64 + lane) * 8];
#pragma unroll
        for (int s = 0; s < 4; ++s)
            acc2[s] = __builtin_amdgcn_mfma_f32_16x16x32_bf16(af[s], bfw, acc2[s], 0, 0, 0);
    }
    __syncthreads();
    {
        int col2 = wave * 16 + ln15;
        float bv = fcb2[col2];
#pragma unroll
        for (int s = 0; s < 4; ++s)
#pragma unroll
            for (int r = 0; r < 4; ++r) {
                int row = s * 16 + quad * 4 + r;
                As[row][col2] = f2bb(fmaxf(acc2[s][r] + bv, 0.f));
            }
    }
    __syncthreads();

    if (tid < 128) {
        int row = tid >> 1, cls = tid & 1;
        int grow = m0 + row;
        if (grow < M) {
            float a = b3s[cls];
#pragma unroll
            for (int k = 0; k < 64; ++k)
                a += b2f(As[row][k]) * w3s[k * 2 + cls];
            out[(size_t)grow * 2 + cls] = a;
        }
    }
}

// ---------------- SpMM: 1 node/wave (64 lanes x ushort2 = 256B/edge), no divergence ----------------
__global__ __launch_bounds__(256)
void spmm_kernel(const int* __restrict__ row_ptr, const int2* __restrict__ epack,
                 const __hip_bfloat16* __restrict__ support,
                 const float* __restrict__ bias, __hip_bfloat16* __restrict__ out,
                 int ldo, int n) {
    int wv = threadIdx.x >> 6;
    int l = threadIdx.x & 63;
    int node = blockIdx.x * 4 + wv;
    if (node >= n) return;
    int start = row_ptr[node], end = row_ptr[node + 1];
    float ax = 0.f, ay = 0.f;
    int p = start;
    for (; p + 4 <= end; p += 4) {
        int2 e0 = epack[p], e1 = epack[p + 1], e2 = epack[p + 2], e3 = epack[p + 3];
        ushort2 u0 = *(const ushort2*)&support[(size_t)e0.x * 128 + l * 2];
        ushort2 u1 = *(const ushort2*)&support[(size_t)e1.x * 128 + l * 2];
        ushort2 u2 = *(const ushort2*)&support[(size_t)e2.x * 128 + l * 2];
        ushort2 u3 = *(const ushort2*)&support[(size_t)e3.x * 128 + l * 2];
        float v0 = __int_as_float(e0.y), v1 = __int_as_float(e1.y);
        float v2 = __int_as_float(e2.y), v3 = __int_as_float(e3.y);
        ax += v0 * b2f(u0.x) + v1 * b2f(u1.x) + v2 * b2f(u2.x) + v3 * b2f(u3.x);
        ay += v0 * b2f(u0.y) + v1 * b2f(u1.y) + v2 * b2f(u2.y) + v3 * b2f(u3.y);
    }
    for (; p < end; ++p) {
        int2 e0 = epack[p];
        float v0 = __int_as_float(e0.y);
        ushort2 u0 = *(const ushort2*)&support[(size_t)e0.x * 128 + l * 2];
        ax += v0 * b2f(u0.x);
        ay += v0 * b2f(u0.y);
    }
    ushort2 ov;
    ov.x = f2bb(fmaxf(ax + bias[l * 2 + 0], 0.f));
    ov.y = f2bb(fmaxf(ay + bias[l * 2 + 1], 0.f));
    *(ushort2*)&out[(size_t)node * ldo + l * 2] = ov;
}

extern "C" void kernel_launch(void* const* d_in, const int* in_sizes, int n_in,
                              void* d_out, int out_size, void* d_ws, size_t ws_size,
                              hipStream_t stream) {
    const int*   adj_row  = (const int*)d_in[0];
    const int*   adj_col  = (const int*)d_in[1];
    const float* adj_vals = (const float*)d_in[2];
    const float* x        = (const float*)d_in[3];
    const float* W1   = (const float*)d_in[5];
    const float* b1   = (const float*)d_in[6];
    const float* W2   = (const float*)d_in[7];
    const float* b2   = (const float*)d_in[8];
    const float* W3   = (const float*)d_in[9];
    const float* b3   = (const float*)d_in[10];
    const float* fcW1 = (const float*)d_in[11];
    const float* fcb1 = (const float*)d_in[12];
    const float* fcW2 = (const float*)d_in[13];
    const float* fcb2 = (const float*)d_in[14];
    const float* fcW3 = (const float*)d_in[15];
    const float* fcb3 = (const float*)d_in[16];
    float* out = (float*)d_out;

    const int N = N_NODES, E = N_EDGES;
    const int Mpad = 50048;

    char* p = (char*)d_ws;
    auto alloc = [&](size_t bytes) {
        char* q = p;
        p += (bytes + 255) & ~(size_t)255;
        return q;
    };
    __hip_bfloat16* featb    = (__hip_bfloat16*)alloc((size_t)Mpad * 384 * 2);
    __hip_bfloat16* supportb = (__hip_bfloat16*)alloc((size_t)Mpad * 128 * 2);
    __hip_bfloat16* pW1   = (__hip_bfloat16*)alloc(16384 * 2);
    __hip_bfloat16* pW2   = (__hip_bfloat16*)alloc(16384 * 2);
    __hip_bfloat16* pW3   = (__hip_bfloat16*)alloc(16384 * 2);
    __hip_bfloat16* pfcW1 = (__hip_bfloat16*)alloc(49152 * 2);
    __hip_bfloat16* pfcW2 = (__hip_bfloat16*)alloc(8192 * 2);
    int*   row_ptr   = (int*)alloc((size_t)(N + 1) * 4);
    int*   bbase     = (int*)alloc((size_t)(NBK + 1) * 4);
    int*   bcursor   = (int*)alloc((size_t)NBK * 4);
    int2*  epack     = (int2*)alloc((size_t)E * 8);
    // tmp slabs alias the tail of featb (dead until spmm1, after binB consumed it)
    int2*  tmp = (int2*)(featb + (size_t)Mpad * 384 - (size_t)NBK * BCAP * 4);

    // ---- prep (weight pack + bucket cursor init), then CSR build ----
    prep_kernel<<<54, 256, 0, stream>>>(W1, W2, W3, fcW1, fcW2,
                                        pW1, pW2, pW3, pfcW1, pfcW2, bcursor);
    binA_kernel<<<cdiv(E, 4096), 256, 0, stream>>>(adj_row, adj_col, adj_vals,
                                                   bcursor, tmp, E);
    bscan_kernel<<<1, 512, 0, stream>>>(bcursor, bbase);
    binB_kernel<<<NBK, 256, 0, stream>>>(tmp, bcursor, bbase, row_ptr, epack, N);

    const int gemmGrid = cdiv(N, 64);
    const int spmmGrid = cdiv(N, 4);

    // ---- GCN layer 1 (A = fp32 x, converted in staging) ----
    mfma_gemm<128, 128, false, false, true><<<gemmGrid, 256, 0, stream>>>(
        x, 128, pW1, nullptr, supportb, 128, N);
    spmm_kernel<<<spmmGrid, 256, 0, stream>>>(row_ptr, epack, supportb, b1,
                                              featb + 0, 384, N);
    // ---- GCN layer 2 ----
    mfma_gemm<128, 128, false, false, false><<<gemmGrid, 256, 0, stream>>>(
        featb + 0, 384, pW2, nullptr, supportb, 128, N);
    spmm_kernel<<<spmmGrid, 256, 0, stream>>>(row_ptr, epack, supportb, b2,
                                              featb + 128, 384, N);
    // ---- GCN layer 3 ----
    mfma_gemm<128, 128, false, false, false><<<gemmGrid, 256, 0, stream>>>(
        featb + 128, 384, pW3, nullptr, supportb, 128, N);
    spmm_kernel<<<spmmGrid, 256, 0, stream>>>(row_ptr, epack, supportb, b3,
                                              featb + 256, 384, N);

    // ---- fused FC head ----
    fc123_kernel<<<gemmGrid, 256, 0, stream>>>(featb, pfcW1, fcb1, pfcW2, fcb2,
                                               fcW3, fcb3, out, N);
}